// Round 1
// baseline (1857.032 us; speedup 1.0000x reference)
//
#include <hip/hip_runtime.h>

#define DIM_C 512
#define HEADS 8
#define HD 64
#define BATCH 2
#define SEQ 4096

// ---------------------------------------------------------------------------
// Generic tiled GEMM with fused bias: C[M,N] = A[M,K] @ W[K,N] + bias[N]
// 64x64 tile, BK=16, 256 threads, 4x4 microtile per thread.
// M,N multiples of 64; K multiple of 16 (true for all uses here).
// ---------------------------------------------------------------------------
__global__ __launch_bounds__(256)
void gemm_bias(const float* __restrict__ A, const float* __restrict__ W,
               const float* __restrict__ bias, float* __restrict__ C,
               int M, int N, int K) {
    __shared__ float As[64][17];   // +1 pad breaks power-of-2 bank stride
    __shared__ float Bs[16][65];

    const int tid = threadIdx.x;
    const int tx = tid & 15;       // 0..15 -> output col group
    const int ty = tid >> 4;       // 0..15 -> output row group
    const int rowBase = blockIdx.y * 64;
    const int colBase = blockIdx.x * 64;

    float acc[4][4] = {};

    for (int k0 = 0; k0 < K; k0 += 16) {
        // A tile 64x16 = 1024 floats = 256 threads x 1 float4
        {
            const int r = tid >> 2;
            const int c = (tid & 3) * 4;
            const float4 a = *reinterpret_cast<const float4*>(
                &A[(size_t)(rowBase + r) * K + k0 + c]);
            As[r][c + 0] = a.x; As[r][c + 1] = a.y;
            As[r][c + 2] = a.z; As[r][c + 3] = a.w;
        }
        // B tile 16x64 = 1024 floats
        {
            const int r = tid >> 4;
            const int c = (tid & 15) * 4;
            const float4 b = *reinterpret_cast<const float4*>(
                &W[(size_t)(k0 + r) * N + colBase + c]);
            Bs[r][c + 0] = b.x; Bs[r][c + 1] = b.y;
            Bs[r][c + 2] = b.z; Bs[r][c + 3] = b.w;
        }
        __syncthreads();

        #pragma unroll
        for (int kk = 0; kk < 16; ++kk) {
            float a[4], b[4];
            #pragma unroll
            for (int i = 0; i < 4; ++i) a[i] = As[ty * 4 + i][kk];
            #pragma unroll
            for (int j = 0; j < 4; ++j) b[j] = Bs[kk][tx * 4 + j];
            #pragma unroll
            for (int i = 0; i < 4; ++i)
                #pragma unroll
                for (int j = 0; j < 4; ++j)
                    acc[i][j] = fmaf(a[i], b[j], acc[i][j]);
        }
        __syncthreads();
    }

    #pragma unroll
    for (int i = 0; i < 4; ++i) {
        const int r = rowBase + ty * 4 + i;
        #pragma unroll
        for (int j = 0; j < 4; ++j) {
            const int c = colBase + tx * 4 + j;
            C[(size_t)r * N + c] = acc[i][j] + bias[c];
        }
    }
}

// ---------------------------------------------------------------------------
// Flash attention, fp32. One block per (q-tile of 64 rows, b*h).
// qkv layout: [B*N, 3*C]; Q at col h*64, K at 512+h*64, V at 1024+h*64.
// Online softmax; Q scaled by 1/sqrt(64) at load.
// aout layout: [B*N, C] (heads re-interleaved) ready for the proj GEMM.
// ---------------------------------------------------------------------------
__global__ __launch_bounds__(256)
void flash_attn(const float* __restrict__ qkv, float* __restrict__ aout) {
    __shared__ float Qs[64][65];
    __shared__ float KVs[64][65];   // reused: K tile, then V tile
    __shared__ float Ps[64][65];

    const int tid = threadIdx.x;
    const int tx = tid & 15;
    const int ty = tid >> 4;
    const int qt = blockIdx.x;
    const int bh = blockIdx.y;
    const int b  = bh >> 3;
    const int h  = bh & 7;

    const size_t rowstride = 3 * DIM_C;
    const size_t base = (size_t)b * SEQ * rowstride + (size_t)h * HD;
    const int q0 = qt * 64;

    // ---- load Q tile (scaled by 1/8) ----
    #pragma unroll
    for (int p = 0; p < 4; ++p) {
        const int idx = tid + p * 256;        // 0..1023
        const int r = idx >> 4;
        const int c = (idx & 15) * 4;
        const float4 v = *reinterpret_cast<const float4*>(
            &qkv[base + (size_t)(q0 + r) * rowstride + c]);
        Qs[r][c + 0] = v.x * 0.125f; Qs[r][c + 1] = v.y * 0.125f;
        Qs[r][c + 2] = v.z * 0.125f; Qs[r][c + 3] = v.w * 0.125f;
    }

    float m[4], l[4], o[4][4];
    #pragma unroll
    for (int i = 0; i < 4; ++i) {
        m[i] = -1e30f; l[i] = 0.f;
        #pragma unroll
        for (int j = 0; j < 4; ++j) o[i][j] = 0.f;
    }

    for (int kt = 0; kt < SEQ / 64; ++kt) {
        const int k0 = kt * 64;
        // ---- load K tile ----
        #pragma unroll
        for (int p = 0; p < 4; ++p) {
            const int idx = tid + p * 256;
            const int r = idx >> 4;
            const int c = (idx & 15) * 4;
            const float4 v = *reinterpret_cast<const float4*>(
                &qkv[base + DIM_C + (size_t)(k0 + r) * rowstride + c]);
            KVs[r][c + 0] = v.x; KVs[r][c + 1] = v.y;
            KVs[r][c + 2] = v.z; KVs[r][c + 3] = v.w;
        }
        __syncthreads();

        // ---- S = (Q*scale) @ K^T  (64x64 tile, 4x4 per thread) ----
        float s[4][4] = {};
        #pragma unroll
        for (int kk = 0; kk < 64; ++kk) {
            float a[4], bb[4];
            #pragma unroll
            for (int i = 0; i < 4; ++i) a[i] = Qs[ty * 4 + i][kk];
            #pragma unroll
            for (int j = 0; j < 4; ++j) bb[j] = KVs[tx * 4 + j][kk];
            #pragma unroll
            for (int i = 0; i < 4; ++i)
                #pragma unroll
                for (int j = 0; j < 4; ++j)
                    s[i][j] = fmaf(a[i], bb[j], s[i][j]);
        }

        // ---- online softmax update (row reduce across the 16 tx lanes) ----
        #pragma unroll
        for (int i = 0; i < 4; ++i) {
            float mm = fmaxf(fmaxf(s[i][0], s[i][1]), fmaxf(s[i][2], s[i][3]));
            #pragma unroll
            for (int d = 1; d < 16; d <<= 1) mm = fmaxf(mm, __shfl_xor(mm, d));
            const float mnew = fmaxf(m[i], mm);
            const float alpha = __expf(m[i] - mnew);
            m[i] = mnew;
            float sum = 0.f;
            #pragma unroll
            for (int j = 0; j < 4; ++j) {
                const float p = __expf(s[i][j] - mnew);
                s[i][j] = p;
                sum += p;
            }
            #pragma unroll
            for (int d = 1; d < 16; d <<= 1) sum += __shfl_xor(sum, d);
            l[i] = l[i] * alpha + sum;
            #pragma unroll
            for (int j = 0; j < 4; ++j) o[i][j] *= alpha;
        }

        // ---- stash P to LDS ----
        #pragma unroll
        for (int i = 0; i < 4; ++i)
            #pragma unroll
            for (int j = 0; j < 4; ++j)
                Ps[ty * 4 + i][tx * 4 + j] = s[i][j];
        __syncthreads();   // P visible; all K reads of KVs done

        // ---- load V tile (reusing KVs) ----
        #pragma unroll
        for (int p = 0; p < 4; ++p) {
            const int idx = tid + p * 256;
            const int r = idx >> 4;
            const int c = (idx & 15) * 4;
            const float4 v = *reinterpret_cast<const float4*>(
                &qkv[base + 2 * DIM_C + (size_t)(k0 + r) * rowstride + c]);
            KVs[r][c + 0] = v.x; KVs[r][c + 1] = v.y;
            KVs[r][c + 2] = v.z; KVs[r][c + 3] = v.w;
        }
        __syncthreads();

        // ---- O += P @ V ----
        #pragma unroll
        for (int kk = 0; kk < 64; ++kk) {
            float a[4], bb[4];
            #pragma unroll
            for (int i = 0; i < 4; ++i) a[i] = Ps[ty * 4 + i][kk];
            #pragma unroll
            for (int j = 0; j < 4; ++j) bb[j] = KVs[kk][tx * 4 + j];
            #pragma unroll
            for (int i = 0; i < 4; ++i)
                #pragma unroll
                for (int j = 0; j < 4; ++j)
                    o[i][j] = fmaf(a[i], bb[j], o[i][j]);
        }
        __syncthreads();   // before next iteration overwrites KVs / Ps
    }

    // ---- normalize and write out in [B*N, C] layout ----
    #pragma unroll
    for (int i = 0; i < 4; ++i) {
        const float inv = 1.0f / l[i];
        const int r = q0 + ty * 4 + i;
        #pragma unroll
        for (int j = 0; j < 4; ++j) {
            aout[((size_t)b * SEQ + r) * DIM_C + h * HD + tx * 4 + j] =
                o[i][j] * inv;
        }
    }
}

// ---------------------------------------------------------------------------
extern "C" void kernel_launch(void* const* d_in, const int* in_sizes, int n_in,
                              void* d_out, int out_size, void* d_ws, size_t ws_size,
                              hipStream_t stream) {
    const float* x      = (const float*)d_in[0];   // [2,4096,512]
    const float* w_qkv  = (const float*)d_in[1];   // [512,1536]
    const float* b_qkv  = (const float*)d_in[2];   // [1536]
    const float* w_proj = (const float*)d_in[3];   // [512,512]
    const float* b_proj = (const float*)d_in[4];   // [512]
    float* out = (float*)d_out;                    // [2,4096,512]

    const int M = BATCH * SEQ;                     // 8192
    float* qkv  = (float*)d_ws;                    // M * 1536 floats (50.3 MB)
    float* aout = qkv + (size_t)M * 3 * DIM_C;     // M * 512 floats (16.8 MB)

    // 1) QKV projection: [8192,512] @ [512,1536] + bias
    {
        dim3 grid(3 * DIM_C / 64, M / 64);
        gemm_bias<<<grid, 256, 0, stream>>>(x, w_qkv, b_qkv, qkv,
                                            M, 3 * DIM_C, DIM_C);
    }
    // 2) Flash attention
    {
        dim3 grid(SEQ / 64, BATCH * HEADS);
        flash_attn<<<grid, 256, 0, stream>>>(qkv, aout);
    }
    // 3) Output projection: [8192,512] @ [512,512] + bias
    {
        dim3 grid(DIM_C / 64, M / 64);
        gemm_bias<<<grid, 256, 0, stream>>>(aout, w_proj, b_proj, out,
                                            M, DIM_C, DIM_C);
    }
}

// Round 2
// 752.296 us; speedup vs baseline: 2.4685x; 2.4685x over previous
//
#include <hip/hip_runtime.h>

#define DIM_C 512
#define HEADS 8
#define HD 64
#define BATCH 2
#define SEQ 4096

typedef __attribute__((ext_vector_type(8))) short short8;
typedef __attribute__((ext_vector_type(4))) float f32x4;

// fp32 -> bf16 round-to-nearest-even
__device__ __forceinline__ ushort f2bf(float f) {
    union { float f; unsigned u; } x; x.f = f;
    unsigned r = x.u + 0x7fffu + ((x.u >> 16) & 1u);
    return (ushort)(r >> 16);
}

// ---------------------------------------------------------------------------
// Tiled fp32 GEMM with fused bias: C[M,N] = A[M,K] @ W[K,N] + bias[N]
// (unchanged from round 1 — converted to MFMA next round if numerics hold)
// ---------------------------------------------------------------------------
__global__ __launch_bounds__(256)
void gemm_bias(const float* __restrict__ A, const float* __restrict__ W,
               const float* __restrict__ bias, float* __restrict__ C,
               int M, int N, int K) {
    __shared__ float As[64][17];
    __shared__ float Bs[16][65];

    const int tid = threadIdx.x;
    const int tx = tid & 15;
    const int ty = tid >> 4;
    const int rowBase = blockIdx.y * 64;
    const int colBase = blockIdx.x * 64;

    float acc[4][4] = {};

    for (int k0 = 0; k0 < K; k0 += 16) {
        {
            const int r = tid >> 2;
            const int c = (tid & 3) * 4;
            const float4 a = *reinterpret_cast<const float4*>(
                &A[(size_t)(rowBase + r) * K + k0 + c]);
            As[r][c + 0] = a.x; As[r][c + 1] = a.y;
            As[r][c + 2] = a.z; As[r][c + 3] = a.w;
        }
        {
            const int r = tid >> 4;
            const int c = (tid & 15) * 4;
            const float4 b = *reinterpret_cast<const float4*>(
                &W[(size_t)(k0 + r) * N + colBase + c]);
            Bs[r][c + 0] = b.x; Bs[r][c + 1] = b.y;
            Bs[r][c + 2] = b.z; Bs[r][c + 3] = b.w;
        }
        __syncthreads();

        #pragma unroll
        for (int kk = 0; kk < 16; ++kk) {
            float a[4], b[4];
            #pragma unroll
            for (int i = 0; i < 4; ++i) a[i] = As[ty * 4 + i][kk];
            #pragma unroll
            for (int j = 0; j < 4; ++j) b[j] = Bs[kk][tx * 4 + j];
            #pragma unroll
            for (int i = 0; i < 4; ++i)
                #pragma unroll
                for (int j = 0; j < 4; ++j)
                    acc[i][j] = fmaf(a[i], b[j], acc[i][j]);
        }
        __syncthreads();
    }

    #pragma unroll
    for (int i = 0; i < 4; ++i) {
        const int r = rowBase + ty * 4 + i;
        #pragma unroll
        for (int j = 0; j < 4; ++j) {
            const int c = colBase + tx * 4 + j;
            C[(size_t)r * N + c] = acc[i][j] + bias[c];
        }
    }
}

// ---------------------------------------------------------------------------
// Flash attention with bf16 MFMA (16x16x32), fp32 accumulate.
// Block = 256 threads = 4 waves; QBLK=64 (16 q-rows/wave), KVBLK=64, D=64.
// LDS tiles bf16 with XOR swizzle: elem_col ^= ((row&7)<<3)  (16B slots).
// K stored row-major [k][d] (B-operand of QK^T reads K rows directly).
// V stored transposed [d][k] (B-operand of PV needs k-contiguous columns).
// P round-trips through per-wave LDS to re-layout C/D -> A-fragment.
// ---------------------------------------------------------------------------
__global__ __launch_bounds__(256)
void flash_attn_mfma(const float* __restrict__ qkv, float* __restrict__ aout) {
    __shared__ alignas(16) ushort Ks[64 * 64];       // 8 KB
    __shared__ alignas(16) ushort Vt[64 * 64];       // 8 KB
    __shared__ alignas(16) ushort Ps[4 * 16 * 64];   // 8 KB (per-wave 16x64)

    const int tid  = threadIdx.x;
    const int lane = tid & 63;
    const int wid  = tid >> 6;
    const int lr   = lane & 15;   // A/B-frag row (m or n), C/D col
    const int lg   = lane >> 4;   // k-group

    const int qt = blockIdx.x;
    const int bh = blockIdx.y;
    const int b  = bh >> 3;
    const int h  = bh & 7;

    const size_t rowstride = 3 * DIM_C;
    const size_t base = (size_t)b * SEQ * rowstride + (size_t)h * HD;
    const int q0 = qt * 64;

    // ---- Q A-fragments in registers, softmax scale (1/8) folded in ----
    short8 qf[2];
    {
        const int qrow = q0 + wid * 16 + lr;
        const float* qp = &qkv[base + (size_t)qrow * rowstride];
        #pragma unroll
        for (int s = 0; s < 2; ++s) {
            const float* p = qp + s * 32 + lg * 8;
            const float4 a = *reinterpret_cast<const float4*>(p);
            const float4 c = *reinterpret_cast<const float4*>(p + 4);
            short8 q;
            q[0] = f2bf(a.x * 0.125f); q[1] = f2bf(a.y * 0.125f);
            q[2] = f2bf(a.z * 0.125f); q[3] = f2bf(a.w * 0.125f);
            q[4] = f2bf(c.x * 0.125f); q[5] = f2bf(c.y * 0.125f);
            q[6] = f2bf(c.z * 0.125f); q[7] = f2bf(c.w * 0.125f);
            qf[s] = q;
        }
    }

    float m[4], l[4];
    f32x4 oa[4];
    #pragma unroll
    for (int r = 0; r < 4; ++r) { m[r] = -1e30f; l[r] = 0.f; }
    #pragma unroll
    for (int dt = 0; dt < 4; ++dt)
        #pragma unroll
        for (int c = 0; c < 4; ++c) oa[dt][c] = 0.f;

    for (int kt = 0; kt < SEQ / 64; ++kt) {
        const int k0 = kt * 64;

        // ---- stage K tile: bf16 row-major [k][64], swizzled ----
        #pragma unroll
        for (int p4 = 0; p4 < 4; ++p4) {
            const int idx = tid + p4 * 256;
            const int k   = idx >> 4;
            const int d4  = (idx & 15) * 4;
            const float4 v = *reinterpret_cast<const float4*>(
                &qkv[base + DIM_C + (size_t)(k0 + k) * rowstride + d4]);
            uint2 w;
            w.x = (unsigned)f2bf(v.x) | ((unsigned)f2bf(v.y) << 16);
            w.y = (unsigned)f2bf(v.z) | ((unsigned)f2bf(v.w) << 16);
            *reinterpret_cast<uint2*>(&Ks[k * 64 + (d4 ^ ((k & 7) << 3))]) = w;
        }
        // ---- stage V tile transposed: bf16 [d][64k], swizzled ----
        #pragma unroll
        for (int p4 = 0; p4 < 4; ++p4) {
            const int idx = tid + p4 * 256;
            const int k   = idx >> 4;
            const int d4  = (idx & 15) * 4;
            const float4 v = *reinterpret_cast<const float4*>(
                &qkv[base + 2 * DIM_C + (size_t)(k0 + k) * rowstride + d4]);
            Vt[(d4 + 0) * 64 + (k ^ (((d4 + 0) & 7) << 3))] = f2bf(v.x);
            Vt[(d4 + 1) * 64 + (k ^ (((d4 + 1) & 7) << 3))] = f2bf(v.y);
            Vt[(d4 + 2) * 64 + (k ^ (((d4 + 2) & 7) << 3))] = f2bf(v.z);
            Vt[(d4 + 3) * 64 + (k ^ (((d4 + 3) & 7) << 3))] = f2bf(v.w);
        }
        __syncthreads();

        // ---- S = Q @ K^T : 4 n-tiles x 2 k-slices of mfma 16x16x32 ----
        f32x4 sa[4];
        #pragma unroll
        for (int t = 0; t < 4; ++t)
            #pragma unroll
            for (int c = 0; c < 4; ++c) sa[t][c] = 0.f;

        #pragma unroll
        for (int t = 0; t < 4; ++t) {
            const int n = t * 16 + lr;      // K row for this lane's B-frag
            #pragma unroll
            for (int s = 0; s < 2; ++s) {
                const short8 kf = *reinterpret_cast<const short8*>(
                    &Ks[n * 64 + ((lg * 8 + 32 * s) ^ ((n & 7) << 3))]);
                sa[t] = __builtin_amdgcn_mfma_f32_16x16x32_bf16(
                    qf[s], kf, sa[t], 0, 0, 0);
            }
        }

        // ---- online softmax; lane holds S[q=lg*4+r][col=t*16+lr] ----
        #pragma unroll
        for (int r = 0; r < 4; ++r) {
            float mm = fmaxf(fmaxf(sa[0][r], sa[1][r]),
                             fmaxf(sa[2][r], sa[3][r]));
            #pragma unroll
            for (int d = 1; d < 16; d <<= 1) mm = fmaxf(mm, __shfl_xor(mm, d));
            const float mnew  = fmaxf(m[r], mm);
            const float alpha = __expf(m[r] - mnew);
            m[r] = mnew;
            float sum = 0.f;
            #pragma unroll
            for (int t = 0; t < 4; ++t) {
                const float p = __expf(sa[t][r] - mnew);
                sa[t][r] = p;
                sum += p;
            }
            #pragma unroll
            for (int d = 1; d < 16; d <<= 1) sum += __shfl_xor(sum, d);
            l[r] = l[r] * alpha + sum;
            #pragma unroll
            for (int dt = 0; dt < 4; ++dt) oa[dt][r] *= alpha;
        }

        // ---- P -> per-wave LDS (bf16, swizzled) to build A-fragments ----
        const int pbase = wid * (16 * 64);
        #pragma unroll
        for (int t = 0; t < 4; ++t) {
            #pragma unroll
            for (int r = 0; r < 4; ++r) {
                const int q = lg * 4 + r;
                const int c = t * 16 + lr;
                Ps[pbase + q * 64 + (c ^ ((q & 7) << 3))] = f2bf(sa[t][r]);
            }
        }
        // (same-wave LDS RAW: compiler inserts lgkmcnt wait)

        // ---- O += P @ V ----
        short8 pf[2];
        #pragma unroll
        for (int s = 0; s < 2; ++s)
            pf[s] = *reinterpret_cast<const short8*>(
                &Ps[pbase + lr * 64 + ((lg * 8 + 32 * s) ^ ((lr & 7) << 3))]);
        #pragma unroll
        for (int dt = 0; dt < 4; ++dt) {
            const int d = dt * 16 + lr;     // V^T row for this lane's B-frag
            #pragma unroll
            for (int s = 0; s < 2; ++s) {
                const short8 vf = *reinterpret_cast<const short8*>(
                    &Vt[d * 64 + ((lg * 8 + 32 * s) ^ ((d & 7) << 3))]);
                oa[dt] = __builtin_amdgcn_mfma_f32_16x16x32_bf16(
                    pf[s], vf, oa[dt], 0, 0, 0);
            }
        }
        __syncthreads();   // before next iteration overwrites Ks/Vt
    }

    // ---- normalize, write out in [B*N, C] layout ----
    #pragma unroll
    for (int r = 0; r < 4; ++r) l[r] = 1.f / l[r];
    const size_t orow0 = (size_t)b * SEQ + q0 + wid * 16;
    #pragma unroll
    for (int dt = 0; dt < 4; ++dt) {
        #pragma unroll
        for (int r = 0; r < 4; ++r) {
            aout[(orow0 + lg * 4 + r) * DIM_C + h * HD + dt * 16 + lr] =
                oa[dt][r] * l[r];
        }
    }
}

// ---------------------------------------------------------------------------
extern "C" void kernel_launch(void* const* d_in, const int* in_sizes, int n_in,
                              void* d_out, int out_size, void* d_ws, size_t ws_size,
                              hipStream_t stream) {
    const float* x      = (const float*)d_in[0];   // [2,4096,512]
    const float* w_qkv  = (const float*)d_in[1];   // [512,1536]
    const float* b_qkv  = (const float*)d_in[2];   // [1536]
    const float* w_proj = (const float*)d_in[3];   // [512,512]
    const float* b_proj = (const float*)d_in[4];   // [512]
    float* out = (float*)d_out;                    // [2,4096,512]

    const int M = BATCH * SEQ;                     // 8192
    float* qkv  = (float*)d_ws;                    // M * 1536 floats
    float* aout = qkv + (size_t)M * 3 * DIM_C;     // M * 512 floats

    // 1) QKV projection
    {
        dim3 grid(3 * DIM_C / 64, M / 64);
        gemm_bias<<<grid, 256, 0, stream>>>(x, w_qkv, b_qkv, qkv,
                                            M, 3 * DIM_C, DIM_C);
    }
    // 2) Flash attention (bf16 MFMA)
    {
        dim3 grid(SEQ / 64, BATCH * HEADS);
        flash_attn_mfma<<<grid, 256, 0, stream>>>(qkv, aout);
    }
    // 3) Output projection
    {
        dim3 grid(DIM_C / 64, M / 64);
        gemm_bias<<<grid, 256, 0, stream>>>(aout, w_proj, b_proj, out,
                                            M, DIM_C, DIM_C);
    }
}

// Round 3
// 358.619 us; speedup vs baseline: 5.1783x; 2.0978x over previous
//
#include <hip/hip_runtime.h>

#define DIM_C 512
#define HEADS 8
#define HD 64
#define BATCH 2
#define SEQ 4096
#define QSCALE (0.125f * 1.44269504088896f)   // 1/sqrt(64) * log2(e)

typedef __attribute__((ext_vector_type(8))) short short8;
typedef __attribute__((ext_vector_type(4))) float f32x4;

// fp32 -> bf16 round-to-nearest-even
__device__ __forceinline__ ushort f2bf(float f) {
    union { float f; unsigned u; } x; x.f = f;
    unsigned r = x.u + 0x7fffu + ((x.u >> 16) & 1u);
    return (ushort)(r >> 16);
}

// async global->LDS, 16B per lane. LDS dest = wave-uniform base + lane*16.
__device__ __forceinline__ void gl_lds16(const void* g, void* l) {
    __builtin_amdgcn_global_load_lds(
        (const __attribute__((address_space(1))) unsigned int*)g,
        (__attribute__((address_space(3))) unsigned int*)l, 16, 0, 0);
}

// ---------------------------------------------------------------------------
// fp32 -> bf16 elementwise (vectorized), n4 = count of float4 groups
// ---------------------------------------------------------------------------
__global__ __launch_bounds__(256)
void convert_bf16(const float* __restrict__ in, ushort* __restrict__ out, int n4) {
    int i = blockIdx.x * blockDim.x + threadIdx.x;
    const int stride = gridDim.x * blockDim.x;
    for (; i < n4; i += stride) {
        const float4 v = reinterpret_cast<const float4*>(in)[i];
        ushort4 o;
        o.x = f2bf(v.x); o.y = f2bf(v.y); o.z = f2bf(v.z); o.w = f2bf(v.w);
        reinterpret_cast<ushort4*>(out)[i] = o;
    }
}

// ---------------------------------------------------------------------------
// fp32 [R][C] -> bf16 [C][R] transpose (weights), 64x64 LDS tiles
// ---------------------------------------------------------------------------
__global__ __launch_bounds__(256)
void transpose_w_bf16(const float* __restrict__ in, ushort* __restrict__ out,
                      int R, int C) {
    __shared__ ushort Ls[64 * 68];
    const int tid = threadIdx.x;
    const int c0 = blockIdx.x * 64, r0 = blockIdx.y * 64;
    #pragma unroll
    for (int p = 0; p < 4; ++p) {
        const int idx = tid + p * 256;
        const int r = idx >> 4, c4 = (idx & 15) * 4;
        const float4 v = *reinterpret_cast<const float4*>(
            &in[(size_t)(r0 + r) * C + c0 + c4]);
        ushort4 o; o.x = f2bf(v.x); o.y = f2bf(v.y); o.z = f2bf(v.z); o.w = f2bf(v.w);
        *reinterpret_cast<ushort4*>(&Ls[r * 68 + c4]) = o;
    }
    __syncthreads();
    #pragma unroll
    for (int p = 0; p < 4; ++p) {
        const int idx = tid + p * 256;
        const int c = idx >> 4, r4 = (idx & 15) * 4;
        ushort4 o;
        o.x = Ls[(r4 + 0) * 68 + c]; o.y = Ls[(r4 + 1) * 68 + c];
        o.z = Ls[(r4 + 2) * 68 + c]; o.w = Ls[(r4 + 3) * 68 + c];
        *reinterpret_cast<ushort4*>(&out[(size_t)(c0 + c) * R + r0 + r4]) = o;
    }
}

// ---------------------------------------------------------------------------
// Extract V from qkvb [B*N,1536] (cols 1024..1535) -> vt[bh][d=64][n=4096] bf16
// ---------------------------------------------------------------------------
__global__ __launch_bounds__(256)
void transpose_v(const ushort* __restrict__ qkvb, ushort* __restrict__ vt) {
    __shared__ ushort Ls[64 * 68];
    const int tid = threadIdx.x;
    const int n0 = blockIdx.x * 64;
    const int bh = blockIdx.y, b = bh >> 3, h = bh & 7;
    #pragma unroll
    for (int p = 0; p < 4; ++p) {
        const int idx = tid + p * 256;
        const int r = idx >> 4, c4 = (idx & 15) * 4;      // r = n-local, c4 = d
        const ushort4 v = *reinterpret_cast<const ushort4*>(
            &qkvb[(size_t)(b * SEQ + n0 + r) * 1536 + 1024 + h * 64 + c4]);
        *reinterpret_cast<ushort4*>(&Ls[r * 68 + c4]) = v;
    }
    __syncthreads();
    #pragma unroll
    for (int p = 0; p < 4; ++p) {
        const int idx = tid + p * 256;
        const int d = idx >> 4, n4 = (idx & 15) * 4;
        ushort4 o;
        o.x = Ls[(n4 + 0) * 68 + d]; o.y = Ls[(n4 + 1) * 68 + d];
        o.z = Ls[(n4 + 2) * 68 + d]; o.w = Ls[(n4 + 3) * 68 + d];
        *reinterpret_cast<ushort4*>(&vt[((size_t)bh * 64 + d) * SEQ + n0 + n4]) = o;
    }
}

// ---------------------------------------------------------------------------
// bf16 MFMA GEMM: C[M,N] = A[M,K] @ BT[N,K]^T + bias.
// 128x128 tile, BK=64, 256 thr = 4 waves (2x2), 4x4 16x16x32 frags per wave.
// Staging via global_load_lds(16B) with inverse-swizzled source chunks;
// LDS rows 128B, chunk swizzle c ^= (row&7)  (T2 / rule #21).
// MODE 0: fp32 out. MODE 1: bf16 out, cols<512 scaled by QSCALE (Q of qkv).
// ---------------------------------------------------------------------------
template<int MODE>
__global__ __launch_bounds__(256)
void gemm_mfma(const ushort* __restrict__ A, const ushort* __restrict__ BT,
               const float* __restrict__ bias, void* __restrict__ Cout,
               int M, int N, int K) {
    __shared__ ushort As[128 * 64];
    __shared__ ushort Bs[128 * 64];
    const int tid = threadIdx.x;
    const int lane = tid & 63, wid = tid >> 6;
    const int lr = lane & 15, lg = lane >> 4;
    const int wm = wid >> 1, wn = wid & 1;
    const int rowBase = blockIdx.y * 128, colBase = blockIdx.x * 128;
    const int l8 = lane >> 3;                       // row within 8-row group
    const int lchunk = (lane & 7) ^ l8;             // inverse-swizzled src chunk

    f32x4 acc[4][4];
    #pragma unroll
    for (int i = 0; i < 4; ++i)
        #pragma unroll
        for (int j = 0; j < 4; ++j)
            #pragma unroll
            for (int c = 0; c < 4; ++c) acc[i][j][c] = 0.f;

    for (int k0 = 0; k0 < K; k0 += 64) {
        #pragma unroll
        for (int i = 0; i < 4; ++i) {
            const int r = wid * 32 + i * 8;
            gl_lds16(&A[(size_t)(rowBase + r + l8) * K + k0 + lchunk * 8],
                     &As[r * 64]);
            gl_lds16(&BT[(size_t)(colBase + r + l8) * K + k0 + lchunk * 8],
                     &Bs[r * 64]);
        }
        __syncthreads();
        #pragma unroll
        for (int s = 0; s < 2; ++s) {
            short8 af[4], bf[4];
            #pragma unroll
            for (int mt = 0; mt < 4; ++mt) {
                const int r = wm * 64 + mt * 16 + lr;
                af[mt] = *reinterpret_cast<const short8*>(
                    &As[r * 64 + ((s * 4 + lg) ^ (r & 7)) * 8]);
            }
            #pragma unroll
            for (int nt = 0; nt < 4; ++nt) {
                const int r = wn * 64 + nt * 16 + lr;
                bf[nt] = *reinterpret_cast<const short8*>(
                    &Bs[r * 64 + ((s * 4 + lg) ^ (r & 7)) * 8]);
            }
            #pragma unroll
            for (int mt = 0; mt < 4; ++mt)
                #pragma unroll
                for (int nt = 0; nt < 4; ++nt)
                    acc[mt][nt] = __builtin_amdgcn_mfma_f32_16x16x32_bf16(
                        af[mt], bf[nt], acc[mt][nt], 0, 0, 0);
        }
        __syncthreads();
    }

    #pragma unroll
    for (int nt = 0; nt < 4; ++nt) {
        const int col = colBase + wn * 64 + nt * 16 + lr;
        const float bv = bias[col];
        const float qs = (MODE == 1 && col < DIM_C) ? QSCALE : 1.f;
        #pragma unroll
        for (int mt = 0; mt < 4; ++mt) {
            #pragma unroll
            for (int j = 0; j < 4; ++j) {
                const int row = rowBase + wm * 64 + mt * 16 + lg * 4 + j;
                const float v = (acc[mt][nt][j] + bv) * qs;
                if (MODE == 0)
                    reinterpret_cast<float*>(Cout)[(size_t)row * N + col] = v;
                else
                    reinterpret_cast<ushort*>(Cout)[(size_t)row * N + col] = f2bf(v);
            }
        }
    }
}

// ---------------------------------------------------------------------------
// Flash attention, all-bf16 inputs, MFMA 16x16x32.
// Q pre-scaled by QSCALE (log2 domain -> exp2f softmax).
// K staged from qkvb, V staged from vt (pre-transposed), both via
// global_load_lds with pre-swizzled source; double-buffered, 1 barrier/tile.
// ---------------------------------------------------------------------------
__global__ __launch_bounds__(256)
void flash_attn2(const ushort* __restrict__ qkvb, const ushort* __restrict__ vt,
                 ushort* __restrict__ aoutb) {
    __shared__ ushort Ks[2][64 * 64];
    __shared__ ushort Vs[2][64 * 64];
    __shared__ ushort Ps[4][16 * 64];

    const int tid = threadIdx.x;
    const int lane = tid & 63, wid = tid >> 6;
    const int lr = lane & 15, lg = lane >> 4;
    const int qt = blockIdx.x, bh = blockIdx.y;
    const int b = bh >> 3, h = bh & 7;
    const int q0 = qt * 64;
    const int l8 = lane >> 3;
    const int lchunk = (lane & 7) ^ l8;

    // Q fragments (already scaled in GEMM epilogue)
    short8 qf[2];
    {
        const size_t qrow = (size_t)b * SEQ + q0 + wid * 16 + lr;
        #pragma unroll
        for (int s = 0; s < 2; ++s)
            qf[s] = *reinterpret_cast<const short8*>(
                &qkvb[qrow * 1536 + h * 64 + s * 32 + lg * 8]);
    }

    float m[4], l[4];
    f32x4 oa[4];
    #pragma unroll
    for (int r = 0; r < 4; ++r) { m[r] = -1e30f; l[r] = 0.f; }
    #pragma unroll
    for (int dt = 0; dt < 4; ++dt)
        #pragma unroll
        for (int c = 0; c < 4; ++c) oa[dt][c] = 0.f;

    auto stage = [&](int kt, int buf) {
        const int k0 = kt * 64;
        #pragma unroll
        for (int i = 0; i < 2; ++i) {
            const int r = wid * 16 + i * 8;
            gl_lds16(&qkvb[(size_t)(b * SEQ + k0 + r + l8) * 1536 + DIM_C +
                           h * 64 + lchunk * 8],
                     &Ks[buf][r * 64]);
            gl_lds16(&vt[((size_t)bh * 64 + r + l8) * SEQ + k0 + lchunk * 8],
                     &Vs[buf][r * 64]);
        }
    };

    stage(0, 0);
    const int NT = SEQ / 64;
    for (int kt = 0; kt < NT; ++kt) {
        const int buf = kt & 1;
        __syncthreads();                       // stage(kt) complete; all waves past t-1
        if (kt + 1 < NT) stage(kt + 1, buf ^ 1);   // prefetch overlaps compute

        // ---- S = Q @ K^T ----
        f32x4 sa[4];
        #pragma unroll
        for (int t = 0; t < 4; ++t)
            #pragma unroll
            for (int c = 0; c < 4; ++c) sa[t][c] = 0.f;
        #pragma unroll
        for (int t = 0; t < 4; ++t) {
            const int n = t * 16 + lr;
            #pragma unroll
            for (int s = 0; s < 2; ++s) {
                const short8 kf = *reinterpret_cast<const short8*>(
                    &Ks[buf][n * 64 + ((s * 4 + lg) ^ (n & 7)) * 8]);
                sa[t] = __builtin_amdgcn_mfma_f32_16x16x32_bf16(
                    qf[s], kf, sa[t], 0, 0, 0);
            }
        }

        // ---- online softmax (log2 domain) ----
        #pragma unroll
        for (int r = 0; r < 4; ++r) {
            float mm = fmaxf(fmaxf(sa[0][r], sa[1][r]),
                             fmaxf(sa[2][r], sa[3][r]));
            #pragma unroll
            for (int d = 1; d < 16; d <<= 1) mm = fmaxf(mm, __shfl_xor(mm, d));
            const float mnew  = fmaxf(m[r], mm);
            const float alpha = exp2f(m[r] - mnew);
            m[r] = mnew;
            float sum = 0.f;
            #pragma unroll
            for (int t = 0; t < 4; ++t) {
                const float p = exp2f(sa[t][r] - mnew);
                sa[t][r] = p;
                sum += p;
            }
            #pragma unroll
            for (int d = 1; d < 16; d <<= 1) sum += __shfl_xor(sum, d);
            l[r] = l[r] * alpha + sum;
            #pragma unroll
            for (int dt = 0; dt < 4; ++dt) oa[dt][r] *= alpha;
        }

        // ---- P -> per-wave LDS (bf16, swizzled) ----
        const int pb = wid * (16 * 64);
        #pragma unroll
        for (int t = 0; t < 4; ++t)
            #pragma unroll
            for (int r = 0; r < 4; ++r) {
                const int q = lg * 4 + r;
                const int c = t * 16 + lr;
                Ps[0][pb + q * 64 + (c ^ ((q & 7) << 3))] = f2bf(sa[t][r]);
            }

        short8 pf[2];
        #pragma unroll
        for (int s = 0; s < 2; ++s)
            pf[s] = *reinterpret_cast<const short8*>(
                &Ps[0][pb + lr * 64 + ((lg * 8 + 32 * s) ^ ((lr & 7) << 3))]);

        // ---- O += P @ V ----
        #pragma unroll
        for (int dt = 0; dt < 4; ++dt) {
            const int d = dt * 16 + lr;
            #pragma unroll
            for (int s = 0; s < 2; ++s) {
                const short8 vf = *reinterpret_cast<const short8*>(
                    &Vs[buf][d * 64 + ((s * 4 + lg) ^ (d & 7)) * 8]);
                oa[dt] = __builtin_amdgcn_mfma_f32_16x16x32_bf16(
                    pf[s], vf, oa[dt], 0, 0, 0);
            }
        }
    }

    // ---- normalize, write bf16 [B*N, C] ----
    #pragma unroll
    for (int r = 0; r < 4; ++r) l[r] = 1.f / l[r];
    const size_t orow0 = (size_t)b * SEQ + q0 + wid * 16;
    #pragma unroll
    for (int dt = 0; dt < 4; ++dt)
        #pragma unroll
        for (int r = 0; r < 4; ++r)
            aoutb[(orow0 + lg * 4 + r) * DIM_C + h * HD + dt * 16 + lr] =
                f2bf(oa[dt][r] * l[r]);
}

// ---------------------------------------------------------------------------
extern "C" void kernel_launch(void* const* d_in, const int* in_sizes, int n_in,
                              void* d_out, int out_size, void* d_ws, size_t ws_size,
                              hipStream_t stream) {
    const float* x      = (const float*)d_in[0];   // [2,4096,512]
    const float* w_qkv  = (const float*)d_in[1];   // [512,1536]
    const float* b_qkv  = (const float*)d_in[2];   // [1536]
    const float* w_proj = (const float*)d_in[3];   // [512,512]
    const float* b_proj = (const float*)d_in[4];   // [512]
    float* out = (float*)d_out;                    // [2,4096,512]

    const int M = BATCH * SEQ;                     // 8192
    ushort* xb     = (ushort*)d_ws;                          // 8192*512
    ushort* wqkvT  = xb     + (size_t)M * DIM_C;             // 1536*512
    ushort* wprojT = wqkvT  + (size_t)3 * DIM_C * DIM_C;     // 512*512
    ushort* qkvb   = wprojT + (size_t)DIM_C * DIM_C;         // 8192*1536
    ushort* vt     = qkvb   + (size_t)M * 3 * DIM_C;         // 16*64*4096
    ushort* aoutb  = vt     + (size_t)16 * HD * SEQ;         // 8192*512

    // prep: bf16 conversions / weight transposes
    convert_bf16<<<2048, 256, 0, stream>>>(x, xb, M * DIM_C / 4);
    transpose_w_bf16<<<dim3(3 * DIM_C / 64, DIM_C / 64), 256, 0, stream>>>(
        w_qkv, wqkvT, DIM_C, 3 * DIM_C);
    transpose_w_bf16<<<dim3(DIM_C / 64, DIM_C / 64), 256, 0, stream>>>(
        w_proj, wprojT, DIM_C, DIM_C);

    // 1) QKV projection (bf16 out, Q pre-scaled)
    gemm_mfma<1><<<dim3(3 * DIM_C / 128, M / 128), 256, 0, stream>>>(
        xb, wqkvT, b_qkv, qkvb, M, 3 * DIM_C, DIM_C);

    // 1b) V transpose -> vt[bh][d][n]
    transpose_v<<<dim3(SEQ / 64, BATCH * HEADS), 256, 0, stream>>>(qkvb, vt);

    // 2) flash attention
    flash_attn2<<<dim3(SEQ / 64, BATCH * HEADS), 256, 0, stream>>>(
        qkvb, vt, aoutb);

    // 3) output projection (fp32 out)
    gemm_mfma<0><<<dim3(DIM_C / 128, M / 128), 256, 0, stream>>>(
        aoutb, wprojT, b_proj, out, M, DIM_C, DIM_C);
}

// Round 6
// 324.982 us; speedup vs baseline: 5.7143x; 1.1035x over previous
//
#include <hip/hip_runtime.h>

#define DIM_C 512
#define HEADS 8
#define HD 64
#define BATCH 2
#define SEQ 4096
#define QSCALE (0.125f * 1.44269504088896f)   // 1/sqrt(64) * log2(e)

typedef __attribute__((ext_vector_type(8))) short short8;
typedef __attribute__((ext_vector_type(4))) float f32x4;

// fp32 -> bf16 round-to-nearest-even
__device__ __forceinline__ ushort f2bf(float f) {
    union { float f; unsigned u; } x; x.f = f;
    unsigned r = x.u + 0x7fffu + ((x.u >> 16) & 1u);
    return (ushort)(r >> 16);
}

// async global->LDS, 16B per lane. LDS dest = wave-uniform base + lane*16.
__device__ __forceinline__ void gl_lds16(const void* g, void* l) {
    __builtin_amdgcn_global_load_lds(
        (const __attribute__((address_space(1))) unsigned int*)g,
        (__attribute__((address_space(3))) unsigned int*)l, 16, 0, 0);
}

__device__ __forceinline__ unsigned cvt_pk_bf16(float lo, float hi) {
    unsigned w;
    asm("v_cvt_pk_bf16_f32 %0, %1, %2" : "=v"(w) : "v"(lo), "v"(hi));
    return w;
}

// ---------------------------------------------------------------------------
// prep kernels (unchanged, proven)
// ---------------------------------------------------------------------------
__global__ __launch_bounds__(256)
void convert_bf16(const float* __restrict__ in, ushort* __restrict__ out, int n4) {
    int i = blockIdx.x * blockDim.x + threadIdx.x;
    const int stride = gridDim.x * blockDim.x;
    for (; i < n4; i += stride) {
        const float4 v = reinterpret_cast<const float4*>(in)[i];
        ushort4 o;
        o.x = f2bf(v.x); o.y = f2bf(v.y); o.z = f2bf(v.z); o.w = f2bf(v.w);
        reinterpret_cast<ushort4*>(out)[i] = o;
    }
}

__global__ __launch_bounds__(256)
void transpose_w_bf16(const float* __restrict__ in, ushort* __restrict__ out,
                      int R, int C) {
    __shared__ ushort Ls[64 * 68];
    const int tid = threadIdx.x;
    const int c0 = blockIdx.x * 64, r0 = blockIdx.y * 64;
    #pragma unroll
    for (int p = 0; p < 4; ++p) {
        const int idx = tid + p * 256;
        const int r = idx >> 4, c4 = (idx & 15) * 4;
        const float4 v = *reinterpret_cast<const float4*>(
            &in[(size_t)(r0 + r) * C + c0 + c4]);
        ushort4 o; o.x = f2bf(v.x); o.y = f2bf(v.y); o.z = f2bf(v.z); o.w = f2bf(v.w);
        *reinterpret_cast<ushort4*>(&Ls[r * 68 + c4]) = o;
    }
    __syncthreads();
    #pragma unroll
    for (int p = 0; p < 4; ++p) {
        const int idx = tid + p * 256;
        const int c = idx >> 4, r4 = (idx & 15) * 4;
        ushort4 o;
        o.x = Ls[(r4 + 0) * 68 + c]; o.y = Ls[(r4 + 1) * 68 + c];
        o.z = Ls[(r4 + 2) * 68 + c]; o.w = Ls[(r4 + 3) * 68 + c];
        *reinterpret_cast<ushort4*>(&out[(size_t)(c0 + c) * R + r0 + r4]) = o;
    }
}

__global__ __launch_bounds__(256)
void transpose_v(const ushort* __restrict__ qkvb, ushort* __restrict__ vt) {
    __shared__ ushort Ls[64 * 68];
    const int tid = threadIdx.x;
    const int n0 = blockIdx.x * 64;
    const int bh = blockIdx.y, b = bh >> 3, h = bh & 7;
    #pragma unroll
    for (int p = 0; p < 4; ++p) {
        const int idx = tid + p * 256;
        const int r = idx >> 4, c4 = (idx & 15) * 4;
        const ushort4 v = *reinterpret_cast<const ushort4*>(
            &qkvb[(size_t)(b * SEQ + n0 + r) * 1536 + 1024 + h * 64 + c4]);
        *reinterpret_cast<ushort4*>(&Ls[r * 68 + c4]) = v;
    }
    __syncthreads();
    #pragma unroll
    for (int p = 0; p < 4; ++p) {
        const int idx = tid + p * 256;
        const int d = idx >> 4, n4 = (idx & 15) * 4;
        ushort4 o;
        o.x = Ls[(n4 + 0) * 68 + d]; o.y = Ls[(n4 + 1) * 68 + d];
        o.z = Ls[(n4 + 2) * 68 + d]; o.w = Ls[(n4 + 3) * 68 + d];
        *reinterpret_cast<ushort4*>(&vt[((size_t)bh * 64 + d) * SEQ + n0 + n4]) = o;
    }
}

// ---------------------------------------------------------------------------
// bf16 MFMA GEMM (unchanged, proven)
// ---------------------------------------------------------------------------
template<int MODE>
__global__ __launch_bounds__(256)
void gemm_mfma(const ushort* __restrict__ A, const ushort* __restrict__ BT,
               const float* __restrict__ bias, void* __restrict__ Cout,
               int M, int N, int K) {
    __shared__ ushort As[128 * 64];
    __shared__ ushort Bs[128 * 64];
    const int tid = threadIdx.x;
    const int lane = tid & 63, wid = tid >> 6;
    const int lr = lane & 15, lg = lane >> 4;
    const int wm = wid >> 1, wn = wid & 1;
    const int rowBase = blockIdx.y * 128, colBase = blockIdx.x * 128;
    const int l8 = lane >> 3;
    const int lchunk = (lane & 7) ^ l8;

    f32x4 acc[4][4];
    #pragma unroll
    for (int i = 0; i < 4; ++i)
        #pragma unroll
        for (int j = 0; j < 4; ++j)
            #pragma unroll
            for (int c = 0; c < 4; ++c) acc[i][j][c] = 0.f;

    for (int k0 = 0; k0 < K; k0 += 64) {
        #pragma unroll
        for (int i = 0; i < 4; ++i) {
            const int r = wid * 32 + i * 8;
            gl_lds16(&A[(size_t)(rowBase + r + l8) * K + k0 + lchunk * 8],
                     &As[r * 64]);
            gl_lds16(&BT[(size_t)(colBase + r + l8) * K + k0 + lchunk * 8],
                     &Bs[r * 64]);
        }
        __syncthreads();
        #pragma unroll
        for (int s = 0; s < 2; ++s) {
            short8 af[4], bf[4];
            #pragma unroll
            for (int mt = 0; mt < 4; ++mt) {
                const int r = wm * 64 + mt * 16 + lr;
                af[mt] = *reinterpret_cast<const short8*>(
                    &As[r * 64 + ((s * 4 + lg) ^ (r & 7)) * 8]);
            }
            #pragma unroll
            for (int nt = 0; nt < 4; ++nt) {
                const int r = wn * 64 + nt * 16 + lr;
                bf[nt] = *reinterpret_cast<const short8*>(
                    &Bs[r * 64 + ((s * 4 + lg) ^ (r & 7)) * 8]);
            }
            #pragma unroll
            for (int mt = 0; mt < 4; ++mt)
                #pragma unroll
                for (int nt = 0; nt < 4; ++nt)
                    acc[mt][nt] = __builtin_amdgcn_mfma_f32_16x16x32_bf16(
                        af[mt], bf[nt], acc[mt][nt], 0, 0, 0);
        }
        __syncthreads();
    }

    #pragma unroll
    for (int nt = 0; nt < 4; ++nt) {
        const int col = colBase + wn * 64 + nt * 16 + lr;
        const float bv = bias[col];
        const float qs = (MODE == 1 && col < DIM_C) ? QSCALE : 1.f;
        #pragma unroll
        for (int mt = 0; mt < 4; ++mt) {
            #pragma unroll
            for (int j = 0; j < 4; ++j) {
                const int row = rowBase + wm * 64 + mt * 16 + lg * 4 + j;
                const float v = (acc[mt][nt][j] + bv) * qs;
                if (MODE == 0)
                    reinterpret_cast<float*>(Cout)[(size_t)row * N + col] = v;
                else
                    reinterpret_cast<ushort*>(Cout)[(size_t)row * N + col] = f2bf(v);
            }
        }
    }
}

// ---------------------------------------------------------------------------
// Flash attention v4 = PROVEN round-3 16x16 structure + three safe deltas:
//   (1) 8 waves / 512 threads, 128 q-rows per block (K/V staged once/block)
//   (2) P-pack via v_cvt_pk_bf16_f32 (same RNE bits, same LDS slots)
//   (3) defer-max: skip rescale when wave-uniformly mx <= m+8 (log2 domain)
// All MFMA fragment layouts byte-identical to the round-3 kernel that passed.
// ---------------------------------------------------------------------------
__global__ __launch_bounds__(512)
void flash_attn4(const ushort* __restrict__ qkvb, const ushort* __restrict__ vt,
                 ushort* __restrict__ aoutb) {
    __shared__ ushort Ks[2][64 * 64];   // 16 KB, [k][d] chunk-swizzled
    __shared__ ushort Vs[2][64 * 64];   // 16 KB, [d][k] chunk-swizzled
    __shared__ ushort Ps[8][16 * 64];   // 16 KB, per-wave P tile

    const int tid = threadIdx.x;
    const int lane = tid & 63, wid = tid >> 6;      // 8 waves
    const int lr = lane & 15, lg = lane >> 4;
    const int qt = blockIdx.x, bh = blockIdx.y;
    const int b = bh >> 3, h = bh & 7;
    const int q0 = qt * 128;
    const int l8 = lane >> 3;
    const int lchunk = (lane & 7) ^ l8;

    // Q A-fragments (pre-scaled by QSCALE in GEMM epilogue)
    short8 qf[2];
    {
        const size_t qrow = (size_t)b * SEQ + q0 + wid * 16 + lr;
        #pragma unroll
        for (int s = 0; s < 2; ++s)
            qf[s] = *reinterpret_cast<const short8*>(
                &qkvb[qrow * 1536 + h * 64 + s * 32 + lg * 8]);
    }

    float m[4], l[4];
    f32x4 oa[4];
    #pragma unroll
    for (int r = 0; r < 4; ++r) { m[r] = -1e30f; l[r] = 0.f; }
    #pragma unroll
    for (int dt = 0; dt < 4; ++dt)
        #pragma unroll
        for (int c = 0; c < 4; ++c) oa[dt][c] = 0.f;

    auto stage = [&](int kt, int buf) {
        const int k0 = kt * 64;
        const int r = wid * 8;                     // 8 waves x 8 rows = 64
        gl_lds16(&qkvb[(size_t)(b * SEQ + k0 + r + l8) * 1536 + DIM_C +
                       h * 64 + lchunk * 8],
                 &Ks[buf][r * 64]);
        gl_lds16(&vt[((size_t)bh * 64 + r + l8) * SEQ + k0 + lchunk * 8],
                 &Vs[buf][r * 64]);
    };

    stage(0, 0);
    const int NT = SEQ / 64;
    for (int kt = 0; kt < NT; ++kt) {
        const int buf = kt & 1;
        __syncthreads();                           // stage(kt) complete
        if (kt + 1 < NT) stage(kt + 1, buf ^ 1);   // prefetch overlaps compute

        // ---- S = Q @ K^T (16x16x32, proven layout) ----
        f32x4 sa[4];
        #pragma unroll
        for (int t = 0; t < 4; ++t)
            #pragma unroll
            for (int c = 0; c < 4; ++c) sa[t][c] = 0.f;
        #pragma unroll
        for (int t = 0; t < 4; ++t) {
            const int n = t * 16 + lr;
            #pragma unroll
            for (int s = 0; s < 2; ++s) {
                const short8 kf = *reinterpret_cast<const short8*>(
                    &Ks[buf][n * 64 + ((s * 4 + lg) ^ (n & 7)) * 8]);
                sa[t] = __builtin_amdgcn_mfma_f32_16x16x32_bf16(
                    qf[s], kf, sa[t], 0, 0, 0);
            }
        }

        // ---- online softmax (log2 domain) with defer-max ----
        float mm[4];
        #pragma unroll
        for (int r = 0; r < 4; ++r) {
            float t = fmaxf(fmaxf(sa[0][r], sa[1][r]),
                            fmaxf(sa[2][r], sa[3][r]));
            #pragma unroll
            for (int d = 1; d < 16; d <<= 1) t = fmaxf(t, __shfl_xor(t, d));
            mm[r] = t;
        }
        const bool need = (mm[0] > m[0] + 8.f) || (mm[1] > m[1] + 8.f) ||
                          (mm[2] > m[2] + 8.f) || (mm[3] > m[3] + 8.f);
        if (__any(need)) {                         // wave-uniform rescale
            #pragma unroll
            for (int r = 0; r < 4; ++r) {
                const float mnew = fmaxf(m[r], mm[r]);
                const float alpha = exp2f(m[r] - mnew);
                m[r] = mnew;
                l[r] *= alpha;
                #pragma unroll
                for (int dt = 0; dt < 4; ++dt) oa[dt][r] *= alpha;
            }
        }
        #pragma unroll
        for (int r = 0; r < 4; ++r) {
            float sum = 0.f;
            #pragma unroll
            for (int t = 0; t < 4; ++t) {
                const float p = exp2f(sa[t][r] - m[r]);
                sa[t][r] = p;
                sum += p;
            }
            #pragma unroll
            for (int d = 1; d < 16; d <<= 1) sum += __shfl_xor(sum, d);
            l[r] += sum;
        }

        // ---- P -> per-wave LDS (cvt_pk conversion, same slots/values) ----
        const int pb = wid * (16 * 64);
        #pragma unroll
        for (int r = 0; r < 4; ++r) {
            const int q = lg * 4 + r;
            const int sw = (q & 7) << 3;
            const unsigned w01 = cvt_pk_bf16(sa[0][r], sa[1][r]);
            const unsigned w23 = cvt_pk_bf16(sa[2][r], sa[3][r]);
            Ps[0][pb + q * 64 + ((0 * 16 + lr) ^ sw)] = (ushort)w01;
            Ps[0][pb + q * 64 + ((1 * 16 + lr) ^ sw)] = (ushort)(w01 >> 16);
            Ps[0][pb + q * 64 + ((2 * 16 + lr) ^ sw)] = (ushort)w23;
            Ps[0][pb + q * 64 + ((3 * 16 + lr) ^ sw)] = (ushort)(w23 >> 16);
        }

        short8 pf[2];
        #pragma unroll
        for (int s = 0; s < 2; ++s)
            pf[s] = *reinterpret_cast<const short8*>(
                &Ps[0][pb + lr * 64 + ((lg * 8 + 32 * s) ^ ((lr & 7) << 3))]);

        // ---- O += P @ V ----
        #pragma unroll
        for (int dt = 0; dt < 4; ++dt) {
            const int d = dt * 16 + lr;
            #pragma unroll
            for (int s = 0; s < 2; ++s) {
                const short8 vf = *reinterpret_cast<const short8*>(
                    &Vs[buf][d * 64 + ((s * 4 + lg) ^ (d & 7)) * 8]);
                oa[dt] = __builtin_amdgcn_mfma_f32_16x16x32_bf16(
                    pf[s], vf, oa[dt], 0, 0, 0);
            }
        }
    }

    // ---- normalize, write bf16 [B*N, C] ----
    #pragma unroll
    for (int r = 0; r < 4; ++r) l[r] = 1.f / l[r];
    const size_t orow0 = (size_t)b * SEQ + q0 + wid * 16;
    #pragma unroll
    for (int dt = 0; dt < 4; ++dt)
        #pragma unroll
        for (int r = 0; r < 4; ++r)
            aoutb[(orow0 + lg * 4 + r) * DIM_C + h * HD + dt * 16 + lr] =
                f2bf(oa[dt][r] * l[r]);
}

// ---------------------------------------------------------------------------
extern "C" void kernel_launch(void* const* d_in, const int* in_sizes, int n_in,
                              void* d_out, int out_size, void* d_ws, size_t ws_size,
                              hipStream_t stream) {
    const float* x      = (const float*)d_in[0];
    const float* w_qkv  = (const float*)d_in[1];
    const float* b_qkv  = (const float*)d_in[2];
    const float* w_proj = (const float*)d_in[3];
    const float* b_proj = (const float*)d_in[4];
    float* out = (float*)d_out;

    const int M = BATCH * SEQ;                               // 8192
    ushort* xb     = (ushort*)d_ws;
    ushort* wqkvT  = xb     + (size_t)M * DIM_C;
    ushort* wprojT = wqkvT  + (size_t)3 * DIM_C * DIM_C;
    ushort* qkvb   = wprojT + (size_t)DIM_C * DIM_C;
    ushort* vt     = qkvb   + (size_t)M * 3 * DIM_C;
    ushort* aoutb  = vt     + (size_t)16 * HD * SEQ;

    convert_bf16<<<2048, 256, 0, stream>>>(x, xb, M * DIM_C / 4);
    transpose_w_bf16<<<dim3(3 * DIM_C / 64, DIM_C / 64), 256, 0, stream>>>(
        w_qkv, wqkvT, DIM_C, 3 * DIM_C);
    transpose_w_bf16<<<dim3(DIM_C / 64, DIM_C / 64), 256, 0, stream>>>(
        w_proj, wprojT, DIM_C, DIM_C);

    gemm_mfma<1><<<dim3(3 * DIM_C / 128, M / 128), 256, 0, stream>>>(
        xb, wqkvT, b_qkv, qkvb, M, 3 * DIM_C, DIM_C);

    transpose_v<<<dim3(SEQ / 64, BATCH * HEADS), 256, 0, stream>>>(qkvb, vt);

    flash_attn4<<<dim3(SEQ / 128, BATCH * HEADS), 512, 0, stream>>>(
        qkvb, vt, aoutb);

    gemm_mfma<0><<<dim3(DIM_C / 128, M / 128), 256, 0, stream>>>(
        aoutb, wprojT, b_proj, out, M, DIM_C, DIM_C);
}

// Round 7
// 256.146 us; speedup vs baseline: 7.2499x; 1.2687x over previous
//
#include <hip/hip_runtime.h>

#define DIM_C 512
#define HEADS 8
#define HD 64
#define BATCH 2
#define SEQ 4096
#define QSCALE (0.125f * 1.44269504088896f)   // 1/sqrt(64) * log2(e)

typedef __attribute__((ext_vector_type(8))) short short8;
typedef __attribute__((ext_vector_type(4))) float f32x4;

// fp32 -> bf16 round-to-nearest-even
__device__ __forceinline__ ushort f2bf(float f) {
    union { float f; unsigned u; } x; x.f = f;
    unsigned r = x.u + 0x7fffu + ((x.u >> 16) & 1u);
    return (ushort)(r >> 16);
}

// async global->LDS, 16B per lane. LDS dest = wave-uniform base + lane*16.
__device__ __forceinline__ void gl_lds16(const void* g, void* l) {
    __builtin_amdgcn_global_load_lds(
        (const __attribute__((address_space(1))) unsigned int*)g,
        (__attribute__((address_space(3))) unsigned int*)l, 16, 0, 0);
}

__device__ __forceinline__ unsigned cvt_pk_bf16(float lo, float hi) {
    unsigned w;
    asm("v_cvt_pk_bf16_f32 %0, %1, %2" : "=v"(w) : "v"(lo), "v"(hi));
    return w;
}

// ---------------------------------------------------------------------------
// prep kernels
// ---------------------------------------------------------------------------
__global__ __launch_bounds__(256)
void convert_bf16(const float* __restrict__ in, ushort* __restrict__ out, int n4) {
    int i = blockIdx.x * blockDim.x + threadIdx.x;
    const int stride = gridDim.x * blockDim.x;
    for (; i < n4; i += stride) {
        const float4 v = reinterpret_cast<const float4*>(in)[i];
        ushort4 o;
        o.x = f2bf(v.x); o.y = f2bf(v.y); o.z = f2bf(v.z); o.w = f2bf(v.w);
        reinterpret_cast<ushort4*>(out)[i] = o;
    }
}

__global__ __launch_bounds__(256)
void transpose_w_bf16(const float* __restrict__ in, ushort* __restrict__ out,
                      int R, int C) {
    __shared__ ushort Ls[64 * 68];
    const int tid = threadIdx.x;
    const int c0 = blockIdx.x * 64, r0 = blockIdx.y * 64;
    #pragma unroll
    for (int p = 0; p < 4; ++p) {
        const int idx = tid + p * 256;
        const int r = idx >> 4, c4 = (idx & 15) * 4;
        const float4 v = *reinterpret_cast<const float4*>(
            &in[(size_t)(r0 + r) * C + c0 + c4]);
        ushort4 o; o.x = f2bf(v.x); o.y = f2bf(v.y); o.z = f2bf(v.z); o.w = f2bf(v.w);
        *reinterpret_cast<ushort4*>(&Ls[r * 68 + c4]) = o;
    }
    __syncthreads();
    #pragma unroll
    for (int p = 0; p < 4; ++p) {
        const int idx = tid + p * 256;
        const int c = idx >> 4, r4 = (idx & 15) * 4;
        ushort4 o;
        o.x = Ls[(r4 + 0) * 68 + c]; o.y = Ls[(r4 + 1) * 68 + c];
        o.z = Ls[(r4 + 2) * 68 + c]; o.w = Ls[(r4 + 3) * 68 + c];
        *reinterpret_cast<ushort4*>(&out[(size_t)(c0 + c) * R + r0 + r4]) = o;
    }
}

// ---------------------------------------------------------------------------
// bf16 MFMA GEMM. MODE 0: fp32 out.
// MODE 1 (QKV): Q cols (<512) scaled by QSCALE -> qkvb; K cols -> qkvb;
//               V cols (>=1024) written TRANSPOSED to vt[bh][d][n] (ushort4).
// ---------------------------------------------------------------------------
template<int MODE>
__global__ __launch_bounds__(256)
void gemm_mfma(const ushort* __restrict__ A, const ushort* __restrict__ BT,
               const float* __restrict__ bias, void* __restrict__ Cout,
               ushort* __restrict__ vtOut, int M, int N, int K) {
    __shared__ ushort As[128 * 64];
    __shared__ ushort Bs[128 * 64];
    const int tid = threadIdx.x;
    const int lane = tid & 63, wid = tid >> 6;
    const int lr = lane & 15, lg = lane >> 4;
    const int wm = wid >> 1, wn = wid & 1;
    const int rowBase = blockIdx.y * 128, colBase = blockIdx.x * 128;
    const int l8 = lane >> 3;
    const int lchunk = (lane & 7) ^ l8;

    f32x4 acc[4][4];
    #pragma unroll
    for (int i = 0; i < 4; ++i)
        #pragma unroll
        for (int j = 0; j < 4; ++j)
            #pragma unroll
            for (int c = 0; c < 4; ++c) acc[i][j][c] = 0.f;

    for (int k0 = 0; k0 < K; k0 += 64) {
        #pragma unroll
        for (int i = 0; i < 4; ++i) {
            const int r = wid * 32 + i * 8;
            gl_lds16(&A[(size_t)(rowBase + r + l8) * K + k0 + lchunk * 8],
                     &As[r * 64]);
            gl_lds16(&BT[(size_t)(colBase + r + l8) * K + k0 + lchunk * 8],
                     &Bs[r * 64]);
        }
        __syncthreads();
        #pragma unroll
        for (int s = 0; s < 2; ++s) {
            short8 af[4], bf[4];
            #pragma unroll
            for (int mt = 0; mt < 4; ++mt) {
                const int r = wm * 64 + mt * 16 + lr;
                af[mt] = *reinterpret_cast<const short8*>(
                    &As[r * 64 + ((s * 4 + lg) ^ (r & 7)) * 8]);
            }
            #pragma unroll
            for (int nt = 0; nt < 4; ++nt) {
                const int r = wn * 64 + nt * 16 + lr;
                bf[nt] = *reinterpret_cast<const short8*>(
                    &Bs[r * 64 + ((s * 4 + lg) ^ (r & 7)) * 8]);
            }
            #pragma unroll
            for (int mt = 0; mt < 4; ++mt)
                #pragma unroll
                for (int nt = 0; nt < 4; ++nt)
                    acc[mt][nt] = __builtin_amdgcn_mfma_f32_16x16x32_bf16(
                        af[mt], bf[nt], acc[mt][nt], 0, 0, 0);
        }
        __syncthreads();
    }

    #pragma unroll
    for (int nt = 0; nt < 4; ++nt) {
        const int col = colBase + wn * 64 + nt * 16 + lr;
        const float bv = bias[col];
        if (MODE == 1 && col >= 1024) {
            // V: write transposed to vt[bh][d][n], 4 consecutive n per store
            const int d = col - 1024;
            const int bb = rowBase >> 12;               // row / SEQ
            const size_t vbase = ((size_t)(bb * 8 + (d >> 6)) * 64 + (d & 63)) * SEQ;
            #pragma unroll
            for (int mt = 0; mt < 4; ++mt) {
                const int n = (rowBase & (SEQ - 1)) + wm * 64 + mt * 16 + lg * 4;
                ushort4 o;
                o.x = f2bf(acc[mt][nt][0] + bv); o.y = f2bf(acc[mt][nt][1] + bv);
                o.z = f2bf(acc[mt][nt][2] + bv); o.w = f2bf(acc[mt][nt][3] + bv);
                *reinterpret_cast<ushort4*>(&vtOut[vbase + n]) = o;
            }
        } else {
            const float qs = (MODE == 1 && col < DIM_C) ? QSCALE : 1.f;
            #pragma unroll
            for (int mt = 0; mt < 4; ++mt) {
                #pragma unroll
                for (int j = 0; j < 4; ++j) {
                    const int row = rowBase + wm * 64 + mt * 16 + lg * 4 + j;
                    const float v = (acc[mt][nt][j] + bv) * qs;
                    if (MODE == 0)
                        reinterpret_cast<float*>(Cout)[(size_t)row * N + col] = v;
                    else
                        reinterpret_cast<ushort*>(Cout)[(size_t)row * N + col] = f2bf(v);
                }
            }
        }
    }
}

// ---------------------------------------------------------------------------
// Flash attention v5: swapped QK^T (S^T in regs -> per-lane row softmax).
//  - mfma(kf, qf): LDS read addresses identical to the proven v4 kernel;
//    C/D now holds S^T[k=t*16+lg*4+r][q=lr]: each lane owns ONE q-row.
//  - softmax: in-lane 15-fmax/add + 2 shfl_xor (16,32) merges; scalar m,l.
//  - P^T write: lane's 16 values -> Ps row lr as 4x ds_write_b64 at
//    chunk-XOR slots; k = t*16+lg*4+r = chunk*8+(lg&1)*4+r, chunk=2t+(lg>>1),
//    addr = lr*64 + (chunk^(lr&7))*8 + (lg&1)*4.  pf-read formula unchanged
//    from v4 (reads chunk c at (c^(lr&7))*8) -> round-trips exactly.
//  - PV and output epilogue unchanged (alpha/linv broadcast via 4 shfl).
// ---------------------------------------------------------------------------
__global__ __launch_bounds__(512)
void flash_attn5(const ushort* __restrict__ qkvb, const ushort* __restrict__ vt,
                 ushort* __restrict__ aoutb) {
    __shared__ ushort Ks[2][64 * 64];   // [k][d] chunk-swizzled
    __shared__ ushort Vs[2][64 * 64];   // [d][k] chunk-swizzled
    __shared__ ushort Ps[8 * 16 * 64];  // per-wave P tile [q][k] chunk-swizzled

    const int tid = threadIdx.x;
    const int lane = tid & 63, wid = tid >> 6;      // 8 waves
    const int lr = lane & 15, lg = lane >> 4;
    const int qt = blockIdx.x, bh = blockIdx.y;
    const int b = bh >> 3, h = bh & 7;
    const int q0 = qt * 128;
    const int l8 = lane >> 3;
    const int lchunk = (lane & 7) ^ l8;

    // Q fragments (pre-scaled by QSCALE); used as B operand (col=lr=q-row)
    short8 qf[2];
    {
        const size_t qrow = (size_t)b * SEQ + q0 + wid * 16 + lr;
        #pragma unroll
        for (int s = 0; s < 2; ++s)
            qf[s] = *reinterpret_cast<const short8*>(
                &qkvb[qrow * 1536 + h * 64 + s * 32 + lg * 8]);
    }

    float m = -1e30f, l = 0.f;                      // per-lane: row q=lr
    f32x4 oa[4];
    #pragma unroll
    for (int dt = 0; dt < 4; ++dt)
        #pragma unroll
        for (int c = 0; c < 4; ++c) oa[dt][c] = 0.f;

    auto stage = [&](int kt, int buf) {
        const int k0 = kt * 64;
        const int r = wid * 8;                      // 8 waves x 8 rows = 64
        gl_lds16(&qkvb[(size_t)(b * SEQ + k0 + r + l8) * 1536 + DIM_C +
                       h * 64 + lchunk * 8],
                 &Ks[buf][r * 64]);
        gl_lds16(&vt[((size_t)bh * 64 + r + l8) * SEQ + k0 + lchunk * 8],
                 &Vs[buf][r * 64]);
    };

    stage(0, 0);
    const int NT = SEQ / 64;
    for (int kt = 0; kt < NT; ++kt) {
        const int buf = kt & 1;
        __syncthreads();                            // stage(kt) complete
        if (kt + 1 < NT) stage(kt + 1, buf ^ 1);    // prefetch overlaps compute

        // ---- S^T = K @ Q^T (swapped operands; same LDS addresses) ----
        f32x4 sa[4];
        #pragma unroll
        for (int t = 0; t < 4; ++t)
            #pragma unroll
            for (int c = 0; c < 4; ++c) sa[t][c] = 0.f;
        #pragma unroll
        for (int t = 0; t < 4; ++t) {
            const int n = t * 16 + lr;
            #pragma unroll
            for (int s = 0; s < 2; ++s) {
                const short8 kf = *reinterpret_cast<const short8*>(
                    &Ks[buf][n * 64 + ((s * 4 + lg) ^ (n & 7)) * 8]);
                sa[t] = __builtin_amdgcn_mfma_f32_16x16x32_bf16(
                    kf, qf[s], sa[t], 0, 0, 0);
            }
        }

        // ---- per-lane row softmax (log2 domain), defer-max THR=8 ----
        float mx = sa[0][0];
        #pragma unroll
        for (int t = 0; t < 4; ++t)
            #pragma unroll
            for (int r = 0; r < 4; ++r) mx = fmaxf(mx, sa[t][r]);
        mx = fmaxf(mx, __shfl_xor(mx, 16));
        mx = fmaxf(mx, __shfl_xor(mx, 32));
        if (__any(mx > m + 8.f)) {                  // rare, wave-uniform
            const float mnew = fmaxf(m, mx);
            const float alpha = exp2f(m - mnew);
            m = mnew;
            l *= alpha;
            const float a0 = __shfl(alpha, lg * 4 + 0);
            const float a1 = __shfl(alpha, lg * 4 + 1);
            const float a2 = __shfl(alpha, lg * 4 + 2);
            const float a3 = __shfl(alpha, lg * 4 + 3);
            #pragma unroll
            for (int dt = 0; dt < 4; ++dt) {
                oa[dt][0] *= a0; oa[dt][1] *= a1;
                oa[dt][2] *= a2; oa[dt][3] *= a3;
            }
        }
        float sum = 0.f;
        #pragma unroll
        for (int t = 0; t < 4; ++t)
            #pragma unroll
            for (int r = 0; r < 4; ++r) {
                sa[t][r] = exp2f(sa[t][r] - m);
                sum += sa[t][r];
            }
        sum += __shfl_xor(sum, 16);
        sum += __shfl_xor(sum, 32);
        l += sum;

        // ---- P^T -> Ps row lr: 4x ds_write_b64 ----
        const int pb = wid * (16 * 64);
        const int pbase = pb + lr * 64 + (lg & 1) * 4;
        #pragma unroll
        for (int t = 0; t < 4; ++t) {
            const int chunk = (2 * t + (lg >> 1)) ^ (lr & 7);
            uint2 w;
            w.x = cvt_pk_bf16(sa[t][0], sa[t][1]);
            w.y = cvt_pk_bf16(sa[t][2], sa[t][3]);
            *reinterpret_cast<uint2*>(&Ps[pbase + chunk * 8]) = w;
        }

        short8 pf[2];
        #pragma unroll
        for (int s = 0; s < 2; ++s)
            pf[s] = *reinterpret_cast<const short8*>(
                &Ps[pb + lr * 64 + ((lg * 8 + 32 * s) ^ ((lr & 7) << 3))]);

        // ---- O += P @ V (unchanged) ----
        #pragma unroll
        for (int dt = 0; dt < 4; ++dt) {
            const int d = dt * 16 + lr;
            #pragma unroll
            for (int s = 0; s < 2; ++s) {
                const short8 vf = *reinterpret_cast<const short8*>(
                    &Vs[buf][d * 64 + ((s * 4 + lg) ^ (d & 7)) * 8]);
                oa[dt] = __builtin_amdgcn_mfma_f32_16x16x32_bf16(
                    pf[s], vf, oa[dt], 0, 0, 0);
            }
        }
    }

    // ---- normalize (broadcast per-row 1/l), write bf16 [B*N, C] ----
    const float linv = 1.f / l;
    const float v0 = __shfl(linv, lg * 4 + 0);
    const float v1 = __shfl(linv, lg * 4 + 1);
    const float v2 = __shfl(linv, lg * 4 + 2);
    const float v3 = __shfl(linv, lg * 4 + 3);
    const size_t orow0 = (size_t)b * SEQ + q0 + wid * 16;
    #pragma unroll
    for (int dt = 0; dt < 4; ++dt) {
        const int c = h * HD + dt * 16 + lr;
        aoutb[(orow0 + lg * 4 + 0) * DIM_C + c] = f2bf(oa[dt][0] * v0);
        aoutb[(orow0 + lg * 4 + 1) * DIM_C + c] = f2bf(oa[dt][1] * v1);
        aoutb[(orow0 + lg * 4 + 2) * DIM_C + c] = f2bf(oa[dt][2] * v2);
        aoutb[(orow0 + lg * 4 + 3) * DIM_C + c] = f2bf(oa[dt][3] * v3);
    }
}

// ---------------------------------------------------------------------------
extern "C" void kernel_launch(void* const* d_in, const int* in_sizes, int n_in,
                              void* d_out, int out_size, void* d_ws, size_t ws_size,
                              hipStream_t stream) {
    const float* x      = (const float*)d_in[0];
    const float* w_qkv  = (const float*)d_in[1];
    const float* b_qkv  = (const float*)d_in[2];
    const float* w_proj = (const float*)d_in[3];
    const float* b_proj = (const float*)d_in[4];
    float* out = (float*)d_out;

    const int M = BATCH * SEQ;                               // 8192
    ushort* xb     = (ushort*)d_ws;
    ushort* wqkvT  = xb     + (size_t)M * DIM_C;
    ushort* wprojT = wqkvT  + (size_t)3 * DIM_C * DIM_C;
    ushort* qkvb   = wprojT + (size_t)DIM_C * DIM_C;
    ushort* vt     = qkvb   + (size_t)M * 3 * DIM_C;
    ushort* aoutb  = vt     + (size_t)16 * HD * SEQ;

    convert_bf16<<<2048, 256, 0, stream>>>(x, xb, M * DIM_C / 4);
    transpose_w_bf16<<<dim3(3 * DIM_C / 64, DIM_C / 64), 256, 0, stream>>>(
        w_qkv, wqkvT, DIM_C, 3 * DIM_C);
    transpose_w_bf16<<<dim3(DIM_C / 64, DIM_C / 64), 256, 0, stream>>>(
        w_proj, wprojT, DIM_C, DIM_C);

    // QKV projection; V written transposed directly to vt
    gemm_mfma<1><<<dim3(3 * DIM_C / 128, M / 128), 256, 0, stream>>>(
        xb, wqkvT, b_qkv, qkvb, vt, M, 3 * DIM_C, DIM_C);

    flash_attn5<<<dim3(SEQ / 128, BATCH * HEADS), 512, 0, stream>>>(
        qkvb, vt, aoutb);

    gemm_mfma<0><<<dim3(DIM_C / 128, M / 128), 256, 0, stream>>>(
        aoutb, wprojT, b_proj, out, nullptr, M, DIM_C, DIM_C);
}

// Round 8
// 254.937 us; speedup vs baseline: 7.2843x; 1.0047x over previous
//
#include <hip/hip_runtime.h>

#define DIM_C 512
#define HEADS 8
#define HD 64
#define BATCH 2
#define SEQ 4096
#define QSCALE (0.125f * 1.44269504088896f)   // 1/sqrt(64) * log2(e)

typedef __attribute__((ext_vector_type(8))) short short8;
typedef __attribute__((ext_vector_type(4))) float f32x4;

// fp32 -> bf16 round-to-nearest-even
__device__ __forceinline__ ushort f2bf(float f) {
    union { float f; unsigned u; } x; x.f = f;
    unsigned r = x.u + 0x7fffu + ((x.u >> 16) & 1u);
    return (ushort)(r >> 16);
}

// async global->LDS, 16B per lane. LDS dest = wave-uniform base + lane*16.
__device__ __forceinline__ void gl_lds16(const void* g, void* l) {
    __builtin_amdgcn_global_load_lds(
        (const __attribute__((address_space(1))) unsigned int*)g,
        (__attribute__((address_space(3))) unsigned int*)l, 16, 0, 0);
}

__device__ __forceinline__ unsigned cvt_pk_bf16(float lo, float hi) {
    unsigned w;
    asm("v_cvt_pk_bf16_f32 %0, %1, %2" : "=v"(w) : "v"(lo), "v"(hi));
    return w;
}

// ---------------------------------------------------------------------------
// prep kernels (proven)
// ---------------------------------------------------------------------------
__global__ __launch_bounds__(256)
void convert_bf16(const float* __restrict__ in, ushort* __restrict__ out, int n4) {
    int i = blockIdx.x * blockDim.x + threadIdx.x;
    const int stride = gridDim.x * blockDim.x;
    for (; i < n4; i += stride) {
        const float4 v = reinterpret_cast<const float4*>(in)[i];
        ushort4 o;
        o.x = f2bf(v.x); o.y = f2bf(v.y); o.z = f2bf(v.z); o.w = f2bf(v.w);
        reinterpret_cast<ushort4*>(out)[i] = o;
    }
}

__global__ __launch_bounds__(256)
void transpose_w_bf16(const float* __restrict__ in, ushort* __restrict__ out,
                      int R, int C) {
    __shared__ ushort Ls[64 * 68];
    const int tid = threadIdx.x;
    const int c0 = blockIdx.x * 64, r0 = blockIdx.y * 64;
    #pragma unroll
    for (int p = 0; p < 4; ++p) {
        const int idx = tid + p * 256;
        const int r = idx >> 4, c4 = (idx & 15) * 4;
        const float4 v = *reinterpret_cast<const float4*>(
            &in[(size_t)(r0 + r) * C + c0 + c4]);
        ushort4 o; o.x = f2bf(v.x); o.y = f2bf(v.y); o.z = f2bf(v.z); o.w = f2bf(v.w);
        *reinterpret_cast<ushort4*>(&Ls[r * 68 + c4]) = o;
    }
    __syncthreads();
    #pragma unroll
    for (int p = 0; p < 4; ++p) {
        const int idx = tid + p * 256;
        const int c = idx >> 4, r4 = (idx & 15) * 4;
        ushort4 o;
        o.x = Ls[(r4 + 0) * 68 + c]; o.y = Ls[(r4 + 1) * 68 + c];
        o.z = Ls[(r4 + 2) * 68 + c]; o.w = Ls[(r4 + 3) * 68 + c];
        *reinterpret_cast<ushort4*>(&out[(size_t)(c0 + c) * R + r0 + r4]) = o;
    }
}

// V extract+transpose: qkvb [B*N,1536] cols 1024.. -> vt[bh][d=64][n=4096]
// (proven round-3/6 kernel, verbatim)
__global__ __launch_bounds__(256)
void transpose_v(const ushort* __restrict__ qkvb, ushort* __restrict__ vt) {
    __shared__ ushort Ls[64 * 68];
    const int tid = threadIdx.x;
    const int n0 = blockIdx.x * 64;
    const int bh = blockIdx.y, b = bh >> 3, h = bh & 7;
    #pragma unroll
    for (int p = 0; p < 4; ++p) {
        const int idx = tid + p * 256;
        const int r = idx >> 4, c4 = (idx & 15) * 4;
        const ushort4 v = *reinterpret_cast<const ushort4*>(
            &qkvb[(size_t)(b * SEQ + n0 + r) * 1536 + 1024 + h * 64 + c4]);
        *reinterpret_cast<ushort4*>(&Ls[r * 68 + c4]) = v;
    }
    __syncthreads();
    #pragma unroll
    for (int p = 0; p < 4; ++p) {
        const int idx = tid + p * 256;
        const int d = idx >> 4, n4 = (idx & 15) * 4;
        ushort4 o;
        o.x = Ls[(n4 + 0) * 68 + d]; o.y = Ls[(n4 + 1) * 68 + d];
        o.z = Ls[(n4 + 2) * 68 + d]; o.w = Ls[(n4 + 3) * 68 + d];
        *reinterpret_cast<ushort4*>(&vt[((size_t)bh * 64 + d) * SEQ + n0 + n4]) = o;
    }
}

// ---------------------------------------------------------------------------
// bf16 MFMA GEMM, SWAPPED operands: mfma(bf, af) so each lane holds one
// C-row (row = ...+lr) and 4 CONSECUTIVE cols (lg*4+j) per acc register.
// Epilogue: MODE 0 -> float4 stores; MODE 1 -> ushort4 stores (Q scaled).
// Staging/fragment loads byte-identical to the proven kernel.
// ---------------------------------------------------------------------------
template<int MODE>
__global__ __launch_bounds__(256)
void gemm_mfma(const ushort* __restrict__ A, const ushort* __restrict__ BT,
               const float* __restrict__ bias, void* __restrict__ Cout,
               int M, int N, int K) {
    __shared__ ushort As[128 * 64];
    __shared__ ushort Bs[128 * 64];
    const int tid = threadIdx.x;
    const int lane = tid & 63, wid = tid >> 6;
    const int lr = lane & 15, lg = lane >> 4;
    const int wm = wid >> 1, wn = wid & 1;
    const int rowBase = blockIdx.y * 128, colBase = blockIdx.x * 128;
    const int l8 = lane >> 3;
    const int lchunk = (lane & 7) ^ l8;

    f32x4 acc[4][4];
    #pragma unroll
    for (int i = 0; i < 4; ++i)
        #pragma unroll
        for (int j = 0; j < 4; ++j)
            #pragma unroll
            for (int c = 0; c < 4; ++c) acc[i][j][c] = 0.f;

    for (int k0 = 0; k0 < K; k0 += 64) {
        #pragma unroll
        for (int i = 0; i < 4; ++i) {
            const int r = wid * 32 + i * 8;
            gl_lds16(&A[(size_t)(rowBase + r + l8) * K + k0 + lchunk * 8],
                     &As[r * 64]);
            gl_lds16(&BT[(size_t)(colBase + r + l8) * K + k0 + lchunk * 8],
                     &Bs[r * 64]);
        }
        __syncthreads();
        #pragma unroll
        for (int s = 0; s < 2; ++s) {
            short8 af[4], bf[4];
            #pragma unroll
            for (int mt = 0; mt < 4; ++mt) {
                const int r = wm * 64 + mt * 16 + lr;
                af[mt] = *reinterpret_cast<const short8*>(
                    &As[r * 64 + ((s * 4 + lg) ^ (r & 7)) * 8]);
            }
            #pragma unroll
            for (int nt = 0; nt < 4; ++nt) {
                const int r = wn * 64 + nt * 16 + lr;
                bf[nt] = *reinterpret_cast<const short8*>(
                    &Bs[r * 64 + ((s * 4 + lg) ^ (r & 7)) * 8]);
            }
            // swapped: C^T accumulation -> lane = one C-row, 4 consecutive cols
            #pragma unroll
            for (int mt = 0; mt < 4; ++mt)
                #pragma unroll
                for (int nt = 0; nt < 4; ++nt)
                    acc[mt][nt] = __builtin_amdgcn_mfma_f32_16x16x32_bf16(
                        bf[nt], af[mt], acc[mt][nt], 0, 0, 0);
        }
        __syncthreads();
    }

    #pragma unroll
    for (int nt = 0; nt < 4; ++nt) {
        const int c0 = colBase + wn * 64 + nt * 16 + lg * 4;
        const float4 bv = *reinterpret_cast<const float4*>(&bias[c0]);
        const float qs = (MODE == 1 && c0 < DIM_C) ? QSCALE : 1.f;
        #pragma unroll
        for (int mt = 0; mt < 4; ++mt) {
            const int row = rowBase + wm * 64 + mt * 16 + lr;
            if (MODE == 0) {
                float4 o;
                o.x = acc[mt][nt][0] + bv.x; o.y = acc[mt][nt][1] + bv.y;
                o.z = acc[mt][nt][2] + bv.z; o.w = acc[mt][nt][3] + bv.w;
                *reinterpret_cast<float4*>(
                    &reinterpret_cast<float*>(Cout)[(size_t)row * N + c0]) = o;
            } else {
                uint2 o;
                o.x = cvt_pk_bf16((acc[mt][nt][0] + bv.x) * qs,
                                  (acc[mt][nt][1] + bv.y) * qs);
                o.y = cvt_pk_bf16((acc[mt][nt][2] + bv.z) * qs,
                                  (acc[mt][nt][3] + bv.w) * qs);
                *reinterpret_cast<uint2*>(
                    &reinterpret_cast<ushort*>(Cout)[(size_t)row * N + c0]) = o;
            }
        }
    }
}

// ---------------------------------------------------------------------------
// Flash attention v5b: proven v5 + (a) Ps chunk XOR extended with
// ((lr>>3)<<2) on BOTH write and read (kills the 4-way ds_write_b64 bank
// conflict; self-consistent involution), (b) s_setprio around MFMA clusters.
// ---------------------------------------------------------------------------
__global__ __launch_bounds__(512)
void flash_attn5(const ushort* __restrict__ qkvb, const ushort* __restrict__ vt,
                 ushort* __restrict__ aoutb) {
    __shared__ ushort Ks[2][64 * 64];   // [k][d] chunk-swizzled
    __shared__ ushort Vs[2][64 * 64];   // [d][k] chunk-swizzled
    __shared__ ushort Ps[8 * 16 * 64];  // per-wave P^T tile

    const int tid = threadIdx.x;
    const int lane = tid & 63, wid = tid >> 6;      // 8 waves
    const int lr = lane & 15, lg = lane >> 4;
    const int qt = blockIdx.x, bh = blockIdx.y;
    const int b = bh >> 3, h = bh & 7;
    const int q0 = qt * 128;
    const int l8 = lane >> 3;
    const int lchunk = (lane & 7) ^ l8;
    const int rsw = (lr & 7) ^ ((lr >> 3) << 2);    // Ps row chunk-swizzle

    // Q fragments (pre-scaled by QSCALE); B operand (col=lr=q-row)
    short8 qf[2];
    {
        const size_t qrow = (size_t)b * SEQ + q0 + wid * 16 + lr;
        #pragma unroll
        for (int s = 0; s < 2; ++s)
            qf[s] = *reinterpret_cast<const short8*>(
                &qkvb[qrow * 1536 + h * 64 + s * 32 + lg * 8]);
    }

    float m = -1e30f, l = 0.f;                      // per-lane: row q=lr
    f32x4 oa[4];
    #pragma unroll
    for (int dt = 0; dt < 4; ++dt)
        #pragma unroll
        for (int c = 0; c < 4; ++c) oa[dt][c] = 0.f;

    auto stage = [&](int kt, int buf) {
        const int k0 = kt * 64;
        const int r = wid * 8;                      // 8 waves x 8 rows = 64
        gl_lds16(&qkvb[(size_t)(b * SEQ + k0 + r + l8) * 1536 + DIM_C +
                       h * 64 + lchunk * 8],
                 &Ks[buf][r * 64]);
        gl_lds16(&vt[((size_t)bh * 64 + r + l8) * SEQ + k0 + lchunk * 8],
                 &Vs[buf][r * 64]);
    };

    stage(0, 0);
    const int NT = SEQ / 64;
    for (int kt = 0; kt < NT; ++kt) {
        const int buf = kt & 1;
        __syncthreads();                            // stage(kt) complete
        if (kt + 1 < NT) stage(kt + 1, buf ^ 1);    // prefetch overlaps compute

        // ---- S^T = K @ Q^T (swapped operands) ----
        f32x4 sa[4];
        #pragma unroll
        for (int t = 0; t < 4; ++t)
            #pragma unroll
            for (int c = 0; c < 4; ++c) sa[t][c] = 0.f;
        __builtin_amdgcn_s_setprio(1);
        #pragma unroll
        for (int t = 0; t < 4; ++t) {
            const int n = t * 16 + lr;
            #pragma unroll
            for (int s = 0; s < 2; ++s) {
                const short8 kf = *reinterpret_cast<const short8*>(
                    &Ks[buf][n * 64 + ((s * 4 + lg) ^ (n & 7)) * 8]);
                sa[t] = __builtin_amdgcn_mfma_f32_16x16x32_bf16(
                    kf, qf[s], sa[t], 0, 0, 0);
            }
        }
        __builtin_amdgcn_s_setprio(0);

        // ---- per-lane row softmax (log2 domain), defer-max THR=8 ----
        float mx = sa[0][0];
        #pragma unroll
        for (int t = 0; t < 4; ++t)
            #pragma unroll
            for (int r = 0; r < 4; ++r) mx = fmaxf(mx, sa[t][r]);
        mx = fmaxf(mx, __shfl_xor(mx, 16));
        mx = fmaxf(mx, __shfl_xor(mx, 32));
        if (__any(mx > m + 8.f)) {                  // rare, wave-uniform
            const float mnew = fmaxf(m, mx);
            const float alpha = exp2f(m - mnew);
            m = mnew;
            l *= alpha;
            const float a0 = __shfl(alpha, lg * 4 + 0);
            const float a1 = __shfl(alpha, lg * 4 + 1);
            const float a2 = __shfl(alpha, lg * 4 + 2);
            const float a3 = __shfl(alpha, lg * 4 + 3);
            #pragma unroll
            for (int dt = 0; dt < 4; ++dt) {
                oa[dt][0] *= a0; oa[dt][1] *= a1;
                oa[dt][2] *= a2; oa[dt][3] *= a3;
            }
        }
        float sum = 0.f;
        #pragma unroll
        for (int t = 0; t < 4; ++t)
            #pragma unroll
            for (int r = 0; r < 4; ++r) {
                sa[t][r] = exp2f(sa[t][r] - m);
                sum += sa[t][r];
            }
        sum += __shfl_xor(sum, 16);
        sum += __shfl_xor(sum, 32);
        l += sum;

        // ---- P^T -> Ps row lr: 4x ds_write_b64, conflict-fixed swizzle ----
        const int pb = wid * (16 * 64);
        const int pbase = pb + lr * 64 + (lg & 1) * 4;
        #pragma unroll
        for (int t = 0; t < 4; ++t) {
            const int chunk = (2 * t + (lg >> 1)) ^ rsw;
            uint2 w;
            w.x = cvt_pk_bf16(sa[t][0], sa[t][1]);
            w.y = cvt_pk_bf16(sa[t][2], sa[t][3]);
            *reinterpret_cast<uint2*>(&Ps[pbase + chunk * 8]) = w;
        }

        short8 pf[2];
        #pragma unroll
        for (int s = 0; s < 2; ++s)
            pf[s] = *reinterpret_cast<const short8*>(
                &Ps[pb + lr * 64 + ((lg + 4 * s) ^ rsw) * 8]);

        // ---- O += P @ V ----
        __builtin_amdgcn_s_setprio(1);
        #pragma unroll
        for (int dt = 0; dt < 4; ++dt) {
            const int d = dt * 16 + lr;
            #pragma unroll
            for (int s = 0; s < 2; ++s) {
                const short8 vf = *reinterpret_cast<const short8*>(
                    &Vs[buf][d * 64 + ((s * 4 + lg) ^ (d & 7)) * 8]);
                oa[dt] = __builtin_amdgcn_mfma_f32_16x16x32_bf16(
                    pf[s], vf, oa[dt], 0, 0, 0);
            }
        }
        __builtin_amdgcn_s_setprio(0);
    }

    // ---- normalize (broadcast per-row 1/l), write bf16 [B*N, C] ----
    const float linv = 1.f / l;
    const float v0 = __shfl(linv, lg * 4 + 0);
    const float v1 = __shfl(linv, lg * 4 + 1);
    const float v2 = __shfl(linv, lg * 4 + 2);
    const float v3 = __shfl(linv, lg * 4 + 3);
    const size_t orow0 = (size_t)b * SEQ + q0 + wid * 16;
    #pragma unroll
    for (int dt = 0; dt < 4; ++dt) {
        const int c = h * HD + dt * 16 + lr;
        aoutb[(orow0 + lg * 4 + 0) * DIM_C + c] = f2bf(oa[dt][0] * v0);
        aoutb[(orow0 + lg * 4 + 1) * DIM_C + c] = f2bf(oa[dt][1] * v1);
        aoutb[(orow0 + lg * 4 + 2) * DIM_C + c] = f2bf(oa[dt][2] * v2);
        aoutb[(orow0 + lg * 4 + 3) * DIM_C + c] = f2bf(oa[dt][3] * v3);
    }
}

// ---------------------------------------------------------------------------
extern "C" void kernel_launch(void* const* d_in, const int* in_sizes, int n_in,
                              void* d_out, int out_size, void* d_ws, size_t ws_size,
                              hipStream_t stream) {
    const float* x      = (const float*)d_in[0];
    const float* w_qkv  = (const float*)d_in[1];
    const float* b_qkv  = (const float*)d_in[2];
    const float* w_proj = (const float*)d_in[3];
    const float* b_proj = (const float*)d_in[4];
    float* out = (float*)d_out;

    const int M = BATCH * SEQ;                               // 8192
    ushort* xb     = (ushort*)d_ws;
    ushort* wqkvT  = xb     + (size_t)M * DIM_C;
    ushort* wprojT = wqkvT  + (size_t)3 * DIM_C * DIM_C;
    ushort* qkvb   = wprojT + (size_t)DIM_C * DIM_C;
    ushort* vt     = qkvb   + (size_t)M * 3 * DIM_C;
    ushort* aoutb  = vt     + (size_t)16 * HD * SEQ;

    convert_bf16<<<2048, 256, 0, stream>>>(x, xb, M * DIM_C / 4);
    transpose_w_bf16<<<dim3(3 * DIM_C / 64, DIM_C / 64), 256, 0, stream>>>(
        w_qkv, wqkvT, DIM_C, 3 * DIM_C);
    transpose_w_bf16<<<dim3(DIM_C / 64, DIM_C / 64), 256, 0, stream>>>(
        w_proj, wprojT, DIM_C, DIM_C);

    // QKV projection (Q scaled; V lands in qkvb, coalesced ushort4)
    gemm_mfma<1><<<dim3(3 * DIM_C / 128, M / 128), 256, 0, stream>>>(
        xb, wqkvT, b_qkv, qkvb, M, 3 * DIM_C, DIM_C);

    transpose_v<<<dim3(SEQ / 64, BATCH * HEADS), 256, 0, stream>>>(qkvb, vt);

    flash_attn5<<<dim3(SEQ / 128, BATCH * HEADS), 512, 0, stream>>>(
        qkvb, vt, aoutb);

    gemm_mfma<0><<<dim3(DIM_C / 128, M / 128), 256, 0, stream>>>(
        aoutb, wprojT, b_proj, out, M, DIM_C, DIM_C);
}